// Round 1
// baseline (197.176 us; speedup 1.0000x reference)
//
#include <hip/hip_runtime.h>
#include <hip/hip_bf16.h>

#define NN 4096      // n_nodes
#define FIN 1433     // in features
#define NH 8         // heads
#define DH 8         // per-head dim
#define HD 64        // NH*DH
#define KP 1472      // K padded to 46*32
#define LOG2E 1.44269504f
#define NJS 8        // j-splits (atomic accumulate -> ws independent of NJS)
#define NCHK ((NN / NJS) / 128)   // 4 chunks of 128 j per block

typedef unsigned int u32;
typedef unsigned long long u64;
typedef float v4f __attribute__((ext_vector_type(4)));
typedef _Float16 f16;
typedef _Float16 h2 __attribute__((ext_vector_type(2)));
typedef _Float16 f16x8 __attribute__((ext_vector_type(8)));

static __device__ __forceinline__ short f2h16(float f) {
    union { f16 h; short s; } u; u.h = (f16)f; return u.s;
}
static __device__ __forceinline__ h2 u2h2(u32 x) {
    union { u32 u; h2 h; } v; v.u = x; return v.h;
}
static __device__ __forceinline__ u32 h22u(h2 x) {
    union { h2 h; u32 u; } v; v.h = x; return v.u;
}

#if __has_builtin(__builtin_amdgcn_sbfe)
#define SBFE1(x, k) __builtin_amdgcn_sbfe((int)(x), (k), 1)
#else
#define SBFE1(x, k) (((int)((x) << (31 - (k)))) >> 31)
#endif

// ---------------- kernel e: edge -> bitmask (2 MB), + zero num/den ----------
// One block per row; lane l covers j = w*1024 + it*64 + l -> ballot gives the
// u64 in natural j-bit order. 67 MB streamed once at full BW, coalesced.
__global__ __launch_bounds__(256) void k_eprep(const int* __restrict__ edge,
                                               u64* __restrict__ emask,
                                               float* __restrict__ zbuf) {
    const int t = threadIdx.x, lane = t & 63, w = t >> 6;
    const int row = blockIdx.x;
    const int* erow = edge + (size_t)row * NN + w * 1024;
    u64* mrow = emask + (size_t)row * (NN / 64) + w * 16;
#pragma unroll
    for (int it = 0; it < 16; ++it) {
        const int e = erow[it * 64 + lane];
        const u64 b = __ballot(e != 0);
        if (lane == 0) mrow[it] = b;
    }
    // zero num (1 MB) + den (128 KB), contiguous: 4096 blocks * 72 = 294912 f32
    if (t < 72) zbuf[row * 72 + t] = 0.f;
}

// ---------------- kernel 0: Wt[n][k] = f16(W[k][n]), k zero-padded to 1472 ---
__global__ __launch_bounds__(256) void k_wprep(const float* __restrict__ W,
                                               short* __restrict__ Wt) {
    __shared__ float Ts[64][65];
    const int c = blockIdx.x;
    const int u = threadIdx.x;
    const int n4 = (u & 15) * 4;
    const int kr = u >> 4;
#pragma unroll
    for (int q = 0; q < 4; ++q) {
        const int kl = kr + q * 16;
        const int kg = c * 64 + kl;
        v4f v = {0.f, 0.f, 0.f, 0.f};
        if (kg < FIN) v = *(const v4f*)&W[(size_t)kg * HD + n4];
        *(v4f*)&Ts[kl][n4] = v;
    }
    __syncthreads();
    const int n = u >> 2;
    const int koff = (u & 3) * 16;
    __align__(16) short tmp[16];
#pragma unroll
    for (int r = 0; r < 16; ++r) tmp[r] = f2h16(Ts[koff + r][n]);
    *(uint4*)&Wt[(size_t)n * KP + c * 64 + koff]     = *(uint4*)&tmp[0];
    *(uint4*)&Wt[(size_t)n * KP + c * 64 + koff + 8] = *(uint4*)&tmp[8];
}

// ---------------- kernel 1: g = vert @ W via f16 MFMA, 8-wave K-split --------
// R13: 4 -> 8 waves per block (512 threads). Grid is 256 blocks = 1 block/CU,
// so 4 waves/CU (1/SIMD) had zero latency hiding for the HBM vert loads; 8
// waves doubles TLP. cacc padded [68] to break the 8-way epilogue bank
// conflict (stride 64 floats == bank-aligned).
__global__ __launch_bounds__(512, 2) void k_gemm(
    const float* __restrict__ vert, const short* __restrict__ Wt,
    const float* __restrict__ al, const float* __restrict__ ar,
    short* __restrict__ gT, short* __restrict__ eB, short* __restrict__ eD,
    float* __restrict__ Rw)
{
    __shared__ float cacc[8][16][68];   // 34.8 KB

    const int t = threadIdx.x, lane = t & 63, w = t >> 6;   // w in 0..7
    const int ml = lane & 15, q = lane >> 4;
    const int i0 = blockIdx.x * 16;
    const float* vrow = vert + (size_t)(i0 + ml) * FIN;

    v4f acc[4];
#pragma unroll
    for (int g = 0; g < 4; ++g) acc[g] = (v4f){0.f, 0.f, 0.f, 0.f};

    for (int c = w; c < 45; c += 8) {
        const int k0 = c * 32 + q * 8;
        v4f a0, a1;
        if (k0 + 7 < FIN) {
            a0 = *(const v4f*)&vrow[k0];
            a1 = *(const v4f*)&vrow[k0 + 4];
        } else {
            float tmp[8];
#pragma unroll
            for (int e = 0; e < 8; ++e)
                tmp[e] = (k0 + e < FIN) ? vrow[k0 + e] : 0.f;
            a0 = (v4f){tmp[0], tmp[1], tmp[2], tmp[3]};
            a1 = (v4f){tmp[4], tmp[5], tmp[6], tmp[7]};
        }
        const f16x8 af = {(f16)a0.x, (f16)a0.y, (f16)a0.z, (f16)a0.w,
                          (f16)a1.x, (f16)a1.y, (f16)a1.z, (f16)a1.w};
#pragma unroll
        for (int g = 0; g < 4; ++g) {
            const f16x8 bf = *(const f16x8*)&Wt[(size_t)(g * 16 + ml) * KP + k0];
            acc[g] = __builtin_amdgcn_mfma_f32_16x16x32_f16(af, bf, acc[g], 0, 0, 0);
        }
    }

#pragma unroll
    for (int g = 0; g < 4; ++g)
#pragma unroll
        for (int r = 0; r < 4; ++r)
            cacc[w][q * 4 + r][g * 16 + ml] = acc[g][r];
    __syncthreads();

    if (t < 256) {
        const int m = t >> 4, n4 = (t & 15) * 4;
        v4f s = (v4f){0.f, 0.f, 0.f, 0.f};
#pragma unroll
        for (int ww = 0; ww < 8; ++ww) s += *(const v4f*)&cacc[ww][m][n4];

#pragma unroll
        for (int e = 0; e < 4; ++e)        // transposed store: gT[hd][node]
            gT[(size_t)(n4 + e) * NN + i0 + m] = f2h16(s[e]);

        float pl = s.x * al[n4] + s.y * al[n4 + 1] + s.z * al[n4 + 2] + s.w * al[n4 + 3];
        float pr = s.x * ar[n4] + s.y * ar[n4 + 1] + s.z * ar[n4 + 2] + s.w * ar[n4 + 3];
        pl += __shfl_xor(pl, 1, 64);
        pr += __shfl_xor(pr, 1, 64);
        if ((t & 1) == 0) {
            const int h = (t & 15) >> 1;
            const int node = i0 + m;
            eB[h * NN + node] = f2h16(exp2f(pr * LOG2E));          // exp(sr)
            eD[h * NN + node] = f2h16(exp2f(0.2f * pr * LOG2E));   // exp(0.2 sr)
            Rw[node * NH + h] = exp2f(-0.8f * pl * LOG2E);         // exp(-0.8 sl)
        }
    }
}

// ---------------- kernel 2: MFMA flash-attn, zero-LDS / zero-barrier ---------
// R13 restructure: edge masks come precompressed from k_eprep (uint4 per lane
// per 128-j chunk); G/B/D fragments are loaded straight from global (gT 512 KB
// + eB/eD 256 KB + emask 2 MB are all L2-resident). No __syncthreads at all;
// latency is hidden by TLP (grid 2048 = 8 blocks/CU). Partial num/den are
// atomically accumulated (buffers zeroed by k_eprep).
// P'[i,j] = max(B_j, R_i*D_j) & mask; ones column (col 8) gives denominator.
__global__ __launch_bounds__(256, 4) void k_attn(
    const uint4* __restrict__ emask, const short* __restrict__ gT,
    const short* __restrict__ eB, const short* __restrict__ eD,
    const float* __restrict__ Rw,
    float* __restrict__ num, float* __restrict__ den)
{
    const int t = threadIdx.x, lane = t & 63, w = t >> 6;
    const int ml = lane & 15, quad = lane >> 4;
    const int i0 = blockIdx.x * 16;
    const int jbase = blockIdx.y * (NN / NJS);
    const int h0 = w, h1 = w + 4;
    const bool mhi = (ml >= 8);
    const u32 one2 = 0x3C003C00u;                 // f16 {1.0, 1.0}
    const uint4 ones4 = (uint4){one2, one2, one2, one2};
    const int qsh = quad * 8;

    h2 Ri[2];
    {
        const f16 r0 = (f16)Rw[(i0 + ml) * NH + h0];
        const f16 r1 = (f16)Rw[(i0 + ml) * NH + h1];
        Ri[0] = (h2){r0, r0};
        Ri[1] = (h2){r1, r1};
    }

    const uint4* mrow = emask + (size_t)(i0 + ml) * (NN / 128) + (jbase >> 7);
    const short* gp0 = gT + (size_t)(h0 * 8 + (ml & 7)) * NN;
    const short* gp1 = gT + (size_t)(h1 * 8 + (ml & 7)) * NN;
    const short* bp0 = eB + (size_t)h0 * NN;
    const short* dp0 = eD + (size_t)h0 * NN;
    const short* bp1 = eB + (size_t)h1 * NN;
    const short* dp1 = eD + (size_t)h1 * NN;

    v4f acc[2];
    acc[0] = (v4f){0.f, 0.f, 0.f, 0.f};
    acc[1] = (v4f){0.f, 0.f, 0.f, 0.f};

    for (int c = 0; c < NCHK; ++c) {
        const uint4 mw = mrow[c];                 // 128 mask bits for this chunk
        const int jc = jbase + c * 128 + qsh;
#pragma unroll
        for (int s = 0; s < 4; ++s) {
            const int j0 = jc + s * 32;
            const uint4 bu0 = *(const uint4*)&bp0[j0];
            const uint4 du0 = *(const uint4*)&dp0[j0];
            const uint4 bu1 = *(const uint4*)&bp1[j0];
            const uint4 du1 = *(const uint4*)&dp1[j0];
            const uint4 gu0 = *(const uint4*)&gp0[j0];
            const uint4 gu1 = *(const uint4*)&gp1[j0];

            const u32 w8 = (&mw.x)[s] >> qsh;     // 8 j-bits for this lane
            u32 m[4];
#pragma unroll
            for (int k = 0; k < 4; ++k) {
                const int ea = SBFE1(w8, 2 * k);            // 0 or 0xFFFFFFFF
                const int eb = SBFE1(w8, 2 * k + 1);
                m[k] = __builtin_amdgcn_perm((u32)eb, (u32)ea, 0x05040100u);
            }
            u32 aw0[4], aw1[4];
#pragma unroll
            for (int k = 0; k < 4; ++k) {
                const u32 rd0 = h22u(Ri[0] * u2h2((&du0.x)[k]));   // v_pk_mul_f16
                const u32 rd1 = h22u(Ri[1] * u2h2((&du1.x)[k]));
                u32 p0, p1;
                asm("v_pk_max_f16 %0, %1, %2" : "=v"(p0) : "v"(rd0), "v"((&bu0.x)[k]));
                asm("v_pk_max_f16 %0, %1, %2" : "=v"(p1) : "v"(rd1), "v"((&bu1.x)[k]));
                aw0[k] = p0 & m[k];
                aw1[k] = p1 & m[k];
            }
            union { uint4 u; f16x8 h; } a0u, a1u, g0u, g1u;
            a0u.u = (uint4){aw0[0], aw0[1], aw0[2], aw0[3]};
            a1u.u = (uint4){aw1[0], aw1[1], aw1[2], aw1[3]};
            g0u.u = mhi ? ones4 : gu0;            // col 8 = ones (denominator)
            g1u.u = mhi ? ones4 : gu1;
            acc[0] = __builtin_amdgcn_mfma_f32_16x16x32_f16(a0u.h, g0u.h, acc[0], 0, 0, 0);
            acc[1] = __builtin_amdgcn_mfma_f32_16x16x32_f16(a1u.h, g1u.h, acc[1], 0, 0, 0);
        }
    }

    // C layout: col = ml (0..7 dims, 8 = denominator), row = quad*4 + r
    const int ibase = i0 + quad * 4;
#pragma unroll
    for (int hh = 0; hh < 2; ++hh) {
        const int h = w + hh * 4;
#pragma unroll
        for (int r = 0; r < 4; ++r) {
            if (ml < 8)
                atomicAdd(&num[(size_t)(ibase + r) * HD + h * 8 + ml], acc[hh][r]);
            else if (ml == 8)
                atomicAdd(&den[(size_t)(ibase + r) * NH + h], acc[hh][r]);
        }
    }
}

// ---------------- kernel 3: divide, ELU --------------------------------------
__global__ __launch_bounds__(256) void k_comb(
    const float* __restrict__ num, const float* __restrict__ den,
    float* __restrict__ out)
{
    const int gid = blockIdx.x * 256 + threadIdx.x;   // 0 .. NN*HD-1
    const int i = gid >> 6, h = (gid & 63) >> 3;
    const float x = num[gid] / den[i * NH + h];
    out[gid] = (x > 0.f) ? x : (__expf(x) - 1.f);     // ELU
}

extern "C" void kernel_launch(void* const* d_in, const int* in_sizes, int n_in,
                              void* d_out, int out_size, void* d_ws, size_t ws_size,
                              hipStream_t stream) {
    const float* vert = (const float*)d_in[0];
    const int*   edge = (const int*)d_in[1];
    const float* W    = (const float*)d_in[2];
    const float* al   = (const float*)d_in[3];
    const float* ar   = (const float*)d_in[4];
    float* out = (float*)d_out;

    char* ws = (char*)d_ws;
    short* gT    = (short*)ws;                          // 512 KB f16 g^T
    short* eB    = (short*)(ws + 512 * 1024);           // 64 KB
    short* eD    = (short*)(ws + 576 * 1024);           // 64 KB
    float* Rw    = (float*)(ws + 640 * 1024);           // 128 KB
    short* Wt    = (short*)(ws + 768 * 1024);           // 184 KB
    u64*   emask = (u64*)(ws + 1024 * 1024);            // 2 MB edge bitmask
    float* num   = (float*)(ws + 3 * 1024 * 1024);      // 1 MB (atomic acc)
    float* den   = (float*)(ws + 4 * 1024 * 1024);      // 128 KB (contiguous after num)

    hipLaunchKernelGGL(k_eprep, dim3(NN), dim3(256), 0, stream, edge, emask, num);
    hipLaunchKernelGGL(k_wprep, dim3(23), dim3(256), 0, stream, W, Wt);
    hipLaunchKernelGGL(k_gemm, dim3(NN / 16), dim3(512), 0, stream,
                       vert, Wt, al, ar, gT, eB, eD, Rw);
    hipLaunchKernelGGL(k_attn, dim3(NN / 16, NJS), dim3(256), 0, stream,
                       (const uint4*)emask, gT, eB, eD, Rw, num, den);
    hipLaunchKernelGGL(k_comb, dim3(NN * HD / 256), dim3(256), 0, stream,
                       num, den, out);
}

// Round 2
// 170.199 us; speedup vs baseline: 1.1585x; 1.1585x over previous
//
#include <hip/hip_runtime.h>
#include <hip/hip_bf16.h>

#define NN 4096      // n_nodes
#define FIN 1433     // in features
#define NH 8         // heads
#define DH 8         // per-head dim
#define HD 64        // NH*DH
#define KP 1472      // K padded to 46*32
#define LOG2E 1.44269504f
#define NJS 4        // j-splits
#define NCHK ((NN / NJS) / 128)   // 8 chunks of 128 j per block

typedef unsigned int u32;
typedef unsigned long long u64;
typedef float v4f __attribute__((ext_vector_type(4)));
typedef _Float16 f16;
typedef _Float16 h2 __attribute__((ext_vector_type(2)));
typedef _Float16 f16x8 __attribute__((ext_vector_type(8)));

static __device__ __forceinline__ short f2h16(float f) {
    union { f16 h; short s; } u; u.h = (f16)f; return u.s;
}
static __device__ __forceinline__ h2 u2h2(u32 x) {
    union { u32 u; h2 h; } v; v.u = x; return v.h;
}
static __device__ __forceinline__ u32 h22u(h2 x) {
    union { h2 h; u32 u; } v; v.h = x; return v.u;
}

#if __has_builtin(__builtin_amdgcn_sbfe)
#define SBFE1(x, k) __builtin_amdgcn_sbfe((int)(x), (k), 1)
#else
#define SBFE1(x, k) (((int)((x) << (31 - (k)))) >> 31)
#endif

// ---------------- kernel e: edge -> bitmask, R12 bit layout ------------------
// Per (row, 128-j chunk): uint4 { evenA_lo, evenA_hi, oddB_lo, oddB_hi }.
// Lane l ballots edge[row][chunk*128 + 2l] (even) / +1 (odd) -> identical bit
// semantics to R12's in-kernel int2 ballots, so k_attn's decode is verbatim.
// 67 MB streamed once, coalesced int2 (8 B/lane = 512 B/wave-instr).
__global__ __launch_bounds__(256) void k_eprep(const int* __restrict__ edge,
                                               uint4* __restrict__ emask) {
    const int t = threadIdx.x, lane = t & 63, w = t >> 6;
    const int row = blockIdx.x;
    const int* erow = edge + (size_t)row * NN;
    uint4* mrow = emask + (size_t)row * (NN / 128);
#pragma unroll
    for (int it = 0; it < 8; ++it) {
        const int ck = w * 8 + it;            // 4 waves x 8 = 32 chunks/row
        const int2 e2 = *(const int2*)&erow[ck * 128 + 2 * lane];
        const u64 bA = __ballot(e2.x != 0);
        const u64 bB = __ballot(e2.y != 0);
        if (lane == 0)
            mrow[ck] = (uint4){(u32)bA, (u32)(bA >> 32), (u32)bB, (u32)(bB >> 32)};
    }
}

// ---------------- kernel 0: Wt[n][k] = f16(W[k][n]), k zero-padded to 1472 ---
__global__ __launch_bounds__(256) void k_wprep(const float* __restrict__ W,
                                               short* __restrict__ Wt) {
    __shared__ float Ts[64][65];
    const int c = blockIdx.x;
    const int u = threadIdx.x;
    const int n4 = (u & 15) * 4;
    const int kr = u >> 4;
#pragma unroll
    for (int q = 0; q < 4; ++q) {
        const int kl = kr + q * 16;
        const int kg = c * 64 + kl;
        v4f v = {0.f, 0.f, 0.f, 0.f};
        if (kg < FIN) v = *(const v4f*)&W[(size_t)kg * HD + n4];
        *(v4f*)&Ts[kl][n4] = v;
    }
    __syncthreads();
    const int n = u >> 2;
    const int koff = (u & 3) * 16;
    __align__(16) short tmp[16];
#pragma unroll
    for (int r = 0; r < 16; ++r) tmp[r] = f2h16(Ts[koff + r][n]);
    *(uint4*)&Wt[(size_t)n * KP + c * 64 + koff]     = *(uint4*)&tmp[0];
    *(uint4*)&Wt[(size_t)n * KP + c * 64 + koff + 8] = *(uint4*)&tmp[8];
}

// ---------------- kernel 1: g = vert @ W via f16 MFMA (R12-proven config) ----
__global__ __launch_bounds__(256, 4) void k_gemm(
    const float* __restrict__ vert, const short* __restrict__ Wt,
    const float* __restrict__ al, const float* __restrict__ ar,
    short* __restrict__ gT, short* __restrict__ eB, short* __restrict__ eD,
    float* __restrict__ Rw)
{
    __shared__ float cacc[4][16][64];   // 16 KB

    const int t = threadIdx.x, lane = t & 63, w = t >> 6;
    const int ml = lane & 15, q = lane >> 4;
    const int i0 = blockIdx.x * 16;
    const float* vrow = vert + (size_t)(i0 + ml) * FIN;

    v4f acc[4];
#pragma unroll
    for (int g = 0; g < 4; ++g) acc[g] = (v4f){0.f, 0.f, 0.f, 0.f};

    for (int c = w; c < 45; c += 4) {
        const int k0 = c * 32 + q * 8;
        v4f a0, a1;
        if (k0 + 7 < FIN) {
            a0 = *(const v4f*)&vrow[k0];
            a1 = *(const v4f*)&vrow[k0 + 4];
        } else {
            float tmp[8];
#pragma unroll
            for (int e = 0; e < 8; ++e)
                tmp[e] = (k0 + e < FIN) ? vrow[k0 + e] : 0.f;
            a0 = (v4f){tmp[0], tmp[1], tmp[2], tmp[3]};
            a1 = (v4f){tmp[4], tmp[5], tmp[6], tmp[7]};
        }
        const f16x8 af = {(f16)a0.x, (f16)a0.y, (f16)a0.z, (f16)a0.w,
                          (f16)a1.x, (f16)a1.y, (f16)a1.z, (f16)a1.w};
#pragma unroll
        for (int g = 0; g < 4; ++g) {
            const f16x8 bf = *(const f16x8*)&Wt[(size_t)(g * 16 + ml) * KP + k0];
            acc[g] = __builtin_amdgcn_mfma_f32_16x16x32_f16(af, bf, acc[g], 0, 0, 0);
        }
    }

#pragma unroll
    for (int g = 0; g < 4; ++g)
#pragma unroll
        for (int r = 0; r < 4; ++r)
            cacc[w][q * 4 + r][g * 16 + ml] = acc[g][r];
    __syncthreads();

    const int m = t >> 4, n4 = (t & 15) * 4;
    v4f s = (v4f){0.f, 0.f, 0.f, 0.f};
#pragma unroll
    for (int ww = 0; ww < 4; ++ww) s += *(const v4f*)&cacc[ww][m][n4];

#pragma unroll
    for (int e = 0; e < 4; ++e)        // transposed store: gT[hd][node]
        gT[(size_t)(n4 + e) * NN + i0 + m] = f2h16(s[e]);

    float pl = s.x * al[n4] + s.y * al[n4 + 1] + s.z * al[n4 + 2] + s.w * al[n4 + 3];
    float pr = s.x * ar[n4] + s.y * ar[n4 + 1] + s.z * ar[n4 + 2] + s.w * ar[n4 + 3];
    pl += __shfl_xor(pl, 1, 64);
    pr += __shfl_xor(pr, 1, 64);
    if ((t & 1) == 0) {
        const int h = (t & 15) >> 1;
        const int node = i0 + m;
        eB[h * NN + node] = f2h16(exp2f(pr * LOG2E));          // exp(sr)
        eD[h * NN + node] = f2h16(exp2f(0.2f * pr * LOG2E));   // exp(0.2 sr)
        Rw[node * NH + h] = exp2f(-0.8f * pl * LOG2E);         // exp(-0.8 sl)
    }
}

// ---------------- kernel 2: MFMA flash-attn, hybrid (R2) ---------------------
// R12 pipelined-LDS structure, minus its two measured costs:
//  - edge stream -> precompressed emask (uint4/lane/chunk, reg-prefetched)
//  - LDS 45.5 -> 34.8 KB: G only (no sB/sD staging, B/D read direct from
//    L1/L2 - 1 line/instr broadcast; no ones row - cndmask on B operand)
//  => exactly 4 blocks/CU (139 KB LDS), grid 1024 = 4/CU, no schedule tail.
// Epilogue: non-atomic NJS partial stores (R1 showed atomics write through
// 16 MB to HBM).
__global__ __launch_bounds__(256, 4) void k_attn(
    const uint4* __restrict__ emask, const short* __restrict__ gT,
    const short* __restrict__ eB, const short* __restrict__ eD,
    const float* __restrict__ Rw,
    float* __restrict__ numw, float* __restrict__ denw)
{
    __shared__ __align__(16) short Gt[2][64][136];  // 34.8 KB

    const int t = threadIdx.x, lane = t & 63, w = t >> 6;
    const int ml = lane & 15, quad = lane >> 4;
    const int m8 = ml & 7;
    const int i0 = blockIdx.x * 16;
    const int js = blockIdx.y;
    const int jbase = js * (NN / NJS);
    const int h0 = w, h1 = w + 4;
    const int qb4 = quad * 4;
    const bool mhi = (ml >= 8);
    const u32 one2 = 0x3C003C00u;                   // f16 {1.0, 1.0}
    const uint4 ones4 = (uint4){one2, one2, one2, one2};

    h2 Ri[2];
    {
        const f16 r0 = (f16)Rw[(i0 + ml) * NH + h0];
        const f16 r1 = (f16)Rw[(i0 + ml) * NH + h1];
        Ri[0] = (h2){r0, r0};
        Ri[1] = (h2){r1, r1};
    }

    const uint4* mrow = emask + (size_t)(i0 + ml) * (NN / 128) + js * NCHK;
    const short* bp0 = eB + (size_t)h0 * NN + jbase;
    const short* dp0 = eD + (size_t)h0 * NN + jbase;
    const short* bp1 = eB + (size_t)h1 * NN + jbase;
    const short* dp1 = eD + (size_t)h1 * NN + jbase;

    const int grow = t >> 3, gseg = (t & 7) * 16;   // 64 rows x 128 j coop stage
    const short* g0 = gT + (size_t)grow * NN + jbase;
    const short* g1 = gT + (size_t)(grow + 32) * NN + jbase;

    {   // stage chunk 0 + mask 0
        *(uint4*)&Gt[0][grow][gseg]          = *(const uint4*)&g0[gseg];
        *(uint4*)&Gt[0][grow][gseg + 8]      = *(const uint4*)&g0[gseg + 8];
        *(uint4*)&Gt[0][grow + 32][gseg]     = *(const uint4*)&g1[gseg];
        *(uint4*)&Gt[0][grow + 32][gseg + 8] = *(const uint4*)&g1[gseg + 8];
    }
    uint4 mw = mrow[0];
    __syncthreads();

    v4f acc[2];
    acc[0] = (v4f){0.f, 0.f, 0.f, 0.f};
    acc[1] = (v4f){0.f, 0.f, 0.f, 0.f};

    for (int c = 0; c < NCHK; ++c) {
        const int cb = c & 1, nb = cb ^ 1;
        const bool pf = (c + 1) < NCHK;
        uint4 pg0, pg1, pg2, pg3, pm;
        if (pf) {   // register-prefetch next G chunk + next mask
            const int jn = (c + 1) * 128;
            pg0 = *(const uint4*)&g0[jn + gseg];
            pg1 = *(const uint4*)&g0[jn + gseg + 8];
            pg2 = *(const uint4*)&g1[jn + gseg];
            pg3 = *(const uint4*)&g1[jn + gseg + 8];
            pm  = mrow[c + 1];
        }
#pragma unroll
        for (int s = 0; s < 4; ++s) {
            const int j0 = c * 128 + s * 32 + quad * 8;
            const uint4 bu0 = *(const uint4*)&bp0[j0];   // direct global (L1/L2)
            const uint4 du0 = *(const uint4*)&dp0[j0];
            const uint4 bu1 = *(const uint4*)&bp1[j0];
            const uint4 du1 = *(const uint4*)&dp1[j0];
            const uint4 gu0 = *(const uint4*)&Gt[cb][h0 * 8 + m8][s * 32 + quad * 8];
            const uint4 gu1 = *(const uint4*)&Gt[cb][h1 * 8 + m8][s * 32 + quad * 8];
            const int base = ((s & 1) << 4) + qb4;
            const u32 WA = ((s >> 1) ? mw.y : mw.x) >> base;   // even-j bits
            const u32 WB = ((s >> 1) ? mw.w : mw.z) >> base;   // odd-j bits
            u32 m[4];
#pragma unroll
            for (int k = 0; k < 4; ++k) {
                const int ea = SBFE1(WA, k);            // 0 or 0xFFFFFFFF
                const int eb = SBFE1(WB, k);
                m[k] = __builtin_amdgcn_perm((u32)eb, (u32)ea, 0x05040100u);
            }
            u32 aw0[4], aw1[4];
#pragma unroll
            for (int k = 0; k < 4; ++k) {
                const u32 rd0 = h22u(Ri[0] * u2h2((&du0.x)[k]));   // v_pk_mul_f16
                const u32 rd1 = h22u(Ri[1] * u2h2((&du1.x)[k]));
                u32 p0, p1;
                asm("v_pk_max_f16 %0, %1, %2" : "=v"(p0) : "v"(rd0), "v"((&bu0.x)[k]));
                asm("v_pk_max_f16 %0, %1, %2" : "=v"(p1) : "v"(rd1), "v"((&bu1.x)[k]));
                aw0[k] = p0 & m[k];
                aw1[k] = p1 & m[k];
            }
            union { uint4 u; f16x8 h; } a0u, a1u, g0u, g1u;
            a0u.u = (uint4){aw0[0], aw0[1], aw0[2], aw0[3]};
            a1u.u = (uint4){aw1[0], aw1[1], aw1[2], aw1[3]};
            g0u.u = mhi ? ones4 : gu0;            // col 8 = ones (denominator)
            g1u.u = mhi ? ones4 : gu1;
            acc[0] = __builtin_amdgcn_mfma_f32_16x16x32_f16(a0u.h, g0u.h, acc[0], 0, 0, 0);
            acc[1] = __builtin_amdgcn_mfma_f32_16x16x32_f16(a1u.h, g1u.h, acc[1], 0, 0, 0);
        }
        if (pf) {   // drain prefetched registers into buffer nb
            *(uint4*)&Gt[nb][grow][gseg]          = pg0;
            *(uint4*)&Gt[nb][grow][gseg + 8]      = pg1;
            *(uint4*)&Gt[nb][grow + 32][gseg]     = pg2;
            *(uint4*)&Gt[nb][grow + 32][gseg + 8] = pg3;
            mw = pm;
        }
        __syncthreads();
    }

    // C layout: col = ml (0..7 dims, 8 = denominator), row = quad*4 + r
    float* nw = numw + (size_t)js * NN * HD;
    float* dw = denw + (size_t)js * NN * NH;
    const int ibase = i0 + quad * 4;
#pragma unroll
    for (int hh = 0; hh < 2; ++hh) {
        const int h = w + hh * 4;
#pragma unroll
        for (int r = 0; r < 4; ++r) {
            if (ml < 8)       nw[(ibase + r) * HD + h * 8 + ml] = acc[hh][r];
            else if (ml == 8) dw[(ibase + r) * NH + h]          = acc[hh][r];
        }
    }
}

// ---------------- kernel 3: combine j-split partials, div, ELU ---------------
__global__ __launch_bounds__(256) void k_comb(
    const float* __restrict__ numw, const float* __restrict__ denw,
    float* __restrict__ out)
{
    const int gid = blockIdx.x * 256 + threadIdx.x;   // 0 .. NN*HD-1
    const int i = gid >> 6, h = (gid & 63) >> 3;
    float num = 0.f, den = 0.f;
#pragma unroll
    for (int s = 0; s < NJS; ++s) {
        num += numw[s * NN * HD + gid];
        den += denw[s * NN * NH + i * NH + h];
    }
    float x = num / den;
    out[gid] = (x > 0.f) ? x : (__expf(x) - 1.f);     // ELU
}

extern "C" void kernel_launch(void* const* d_in, const int* in_sizes, int n_in,
                              void* d_out, int out_size, void* d_ws, size_t ws_size,
                              hipStream_t stream) {
    const float* vert = (const float*)d_in[0];
    const int*   edge = (const int*)d_in[1];
    const float* W    = (const float*)d_in[2];
    const float* al   = (const float*)d_in[3];
    const float* ar   = (const float*)d_in[4];
    float* out = (float*)d_out;

    char* ws = (char*)d_ws;
    short* gT    = (short*)ws;                          // 512 KB f16 g^T
    short* eB    = (short*)(ws + 512 * 1024);           // 64 KB
    short* eD    = (short*)(ws + 576 * 1024);           // 64 KB
    float* Rw    = (float*)(ws + 640 * 1024);           // 128 KB
    short* Wt    = (short*)(ws + 768 * 1024);           // 184 KB
    uint4* emask = (uint4*)(ws + 1024 * 1024);          // 2 MB edge bitmask
    float* numw  = (float*)(ws + 3 * 1024 * 1024);      // 4 MB (4 splits)
    float* denw  = (float*)(ws + 7 * 1024 * 1024);      // 512 KB

    hipLaunchKernelGGL(k_eprep, dim3(NN), dim3(256), 0, stream, edge, emask);
    hipLaunchKernelGGL(k_wprep, dim3(23), dim3(256), 0, stream, W, Wt);
    hipLaunchKernelGGL(k_gemm, dim3(NN / 16), dim3(256), 0, stream,
                       vert, Wt, al, ar, gT, eB, eD, Rw);
    hipLaunchKernelGGL(k_attn, dim3(NN / 16, NJS), dim3(256), 0, stream,
                       emask, gT, eB, eD, Rw, numw, denw);
    hipLaunchKernelGGL(k_comb, dim3(NN * HD / 256), dim3(256), 0, stream,
                       numw, denw, out);
}

// Round 3
// 161.462 us; speedup vs baseline: 1.2212x; 1.0541x over previous
//
#include <hip/hip_runtime.h>
#include <hip/hip_bf16.h>

#define NN 4096      // n_nodes
#define FIN 1433     // in features
#define NH 8         // heads
#define DH 8         // per-head dim
#define HD 64        // NH*DH
#define KP 1472      // K padded to 46*32
#define LOG2E 1.44269504f
#define NJS 8        // j-splits: grid 2048 = exactly 8 blocks/CU
#define NCHK ((NN / NJS) / 128)   // 4 chunks of 128 j per block
#define NKS 4        // gemm K-splits: grid 1024 = 4 blocks/CU

typedef unsigned int u32;
typedef unsigned long long u64;
typedef float v4f __attribute__((ext_vector_type(4)));
typedef _Float16 f16;
typedef _Float16 h2 __attribute__((ext_vector_type(2)));
typedef _Float16 f16x8 __attribute__((ext_vector_type(8)));

static __device__ __forceinline__ short f2h16(float f) {
    union { f16 h; short s; } u; u.h = (f16)f; return u.s;
}
static __device__ __forceinline__ h2 u2h2(u32 x) {
    union { u32 u; h2 h; } v; v.u = x; return v.h;
}
static __device__ __forceinline__ u32 h22u(h2 x) {
    union { h2 h; u32 u; } v; v.h = x; return v.u;
}

#if __has_builtin(__builtin_amdgcn_sbfe)
#define SBFE1(x, k) __builtin_amdgcn_sbfe((int)(x), (k), 1)
#else
#define SBFE1(x, k) (((int)((x) << (31 - (k)))) >> 31)
#endif

// ---------------- kernel e: edge -> bitmask, R12 bit layout ------------------
// Per (row, 128-j chunk): uint4 { evenA_lo, evenA_hi, oddB_lo, oddB_hi }.
// 67 MB streamed once, coalesced int2 (8 B/lane). At the HBM BW floor (~11us).
__global__ __launch_bounds__(256) void k_eprep(const int* __restrict__ edge,
                                               uint4* __restrict__ emask) {
    const int t = threadIdx.x, lane = t & 63, w = t >> 6;
    const int row = blockIdx.x;
    const int* erow = edge + (size_t)row * NN;
    uint4* mrow = emask + (size_t)row * (NN / 128);
#pragma unroll
    for (int it = 0; it < 8; ++it) {
        const int ck = w * 8 + it;            // 4 waves x 8 = 32 chunks/row
        const int2 e2 = *(const int2*)&erow[ck * 128 + 2 * lane];
        const u64 bA = __ballot(e2.x != 0);
        const u64 bB = __ballot(e2.y != 0);
        if (lane == 0)
            mrow[ck] = (uint4){(u32)bA, (u32)(bA >> 32), (u32)bB, (u32)(bB >> 32)};
    }
}

// ---------------- kernel 0: Wt[n][k] = f16(W[k][n]), k zero-padded to 1472 ---
__global__ __launch_bounds__(256) void k_wprep(const float* __restrict__ W,
                                               short* __restrict__ Wt) {
    __shared__ float Ts[64][65];
    const int c = blockIdx.x;
    const int u = threadIdx.x;
    const int n4 = (u & 15) * 4;
    const int kr = u >> 4;
#pragma unroll
    for (int q = 0; q < 4; ++q) {
        const int kl = kr + q * 16;
        const int kg = c * 64 + kl;
        v4f v = {0.f, 0.f, 0.f, 0.f};
        if (kg < FIN) v = *(const v4f*)&W[(size_t)kg * HD + n4];
        *(v4f*)&Ts[kl][n4] = v;
    }
    __syncthreads();
    const int n = u >> 2;
    const int koff = (u & 3) * 16;
    __align__(16) short tmp[16];
#pragma unroll
    for (int r = 0; r < 16; ++r) tmp[r] = f2h16(Ts[koff + r][n]);
    *(uint4*)&Wt[(size_t)n * KP + c * 64 + koff]     = *(uint4*)&tmp[0];
    *(uint4*)&Wt[(size_t)n * KP + c * 64 + koff + 8] = *(uint4*)&tmp[8];
}

// ---------------- kernel 1: g = vert @ W, K-split x4 across blocks -----------
// R3: grid (256, NKS) = 1024 blocks = 4 blocks/CU (was 1/CU = 1 wave/SIMD with
// zero latency hiding for the serial HBM vert-load chain). Each K-chunk is
// read by exactly one block -> vert HBM traffic unchanged. f32 partials to
// Cp[ks][node][hd]; reduction + epilogue moved to k_gpost.
__global__ __launch_bounds__(256, 4) void k_gemm(
    const float* __restrict__ vert, const short* __restrict__ Wt,
    float* __restrict__ Cp)
{
    __shared__ float cacc[4][16][68];   // 17.4 KB

    const int t = threadIdx.x, lane = t & 63, w = t >> 6;
    const int ml = lane & 15, q = lane >> 4;
    const int i0 = blockIdx.x * 16;
    const int ks = blockIdx.y;
    const float* vrow = vert + (size_t)(i0 + ml) * FIN;

    v4f acc[4];
#pragma unroll
    for (int g = 0; g < 4; ++g) acc[g] = (v4f){0.f, 0.f, 0.f, 0.f};

    // chunk c handled by block ks = c%4, wave w = (c>>2)%4: covers 0..44 once
    for (int c = ks + 4 * w; c < 45; c += 16) {
        const int k0 = c * 32 + q * 8;
        v4f a0, a1;
        if (k0 + 7 < FIN) {
            a0 = *(const v4f*)&vrow[k0];
            a1 = *(const v4f*)&vrow[k0 + 4];
        } else {
            float tmp[8];
#pragma unroll
            for (int e = 0; e < 8; ++e)
                tmp[e] = (k0 + e < FIN) ? vrow[k0 + e] : 0.f;
            a0 = (v4f){tmp[0], tmp[1], tmp[2], tmp[3]};
            a1 = (v4f){tmp[4], tmp[5], tmp[6], tmp[7]};
        }
        const f16x8 af = {(f16)a0.x, (f16)a0.y, (f16)a0.z, (f16)a0.w,
                          (f16)a1.x, (f16)a1.y, (f16)a1.z, (f16)a1.w};
#pragma unroll
        for (int g = 0; g < 4; ++g) {
            const f16x8 bf = *(const f16x8*)&Wt[(size_t)(g * 16 + ml) * KP + k0];
            acc[g] = __builtin_amdgcn_mfma_f32_16x16x32_f16(af, bf, acc[g], 0, 0, 0);
        }
    }

#pragma unroll
    for (int g = 0; g < 4; ++g)
#pragma unroll
        for (int r = 0; r < 4; ++r)
            cacc[w][q * 4 + r][g * 16 + ml] = acc[g][r];
    __syncthreads();

    const int m = t >> 4, n4 = (t & 15) * 4;
    v4f s = (v4f){0.f, 0.f, 0.f, 0.f};
#pragma unroll
    for (int ww = 0; ww < 4; ++ww) s += *(const v4f*)&cacc[ww][m][n4];
    *(v4f*)&Cp[((size_t)ks * NN + i0 + m) * HD + n4] = s;
}

// ---------------- kernel 1b: reduce K-partials + epilogue --------------------
__global__ __launch_bounds__(256) void k_gpost(
    const float* __restrict__ Cp,
    const float* __restrict__ al, const float* __restrict__ ar,
    short* __restrict__ gT, short* __restrict__ eB, short* __restrict__ eD,
    float* __restrict__ Rw)
{
    const int t = threadIdx.x;
    const int gid = blockIdx.x * 256 + t;        // 0 .. NN*16-1
    const int i = gid >> 4, n4 = (gid & 15) * 4;

    v4f s = (v4f){0.f, 0.f, 0.f, 0.f};
#pragma unroll
    for (int ks = 0; ks < NKS; ++ks)
        s += *(const v4f*)&Cp[((size_t)ks * NN + i) * HD + n4];

#pragma unroll
    for (int e = 0; e < 4; ++e)        // transposed store: gT[hd][node]
        gT[(size_t)(n4 + e) * NN + i] = f2h16(s[e]);

    float pl = s.x * al[n4] + s.y * al[n4 + 1] + s.z * al[n4 + 2] + s.w * al[n4 + 3];
    float pr = s.x * ar[n4] + s.y * ar[n4 + 1] + s.z * ar[n4 + 2] + s.w * ar[n4 + 3];
    pl += __shfl_xor(pl, 1, 64);
    pr += __shfl_xor(pr, 1, 64);
    if ((t & 1) == 0) {
        const int h = (t & 15) >> 1;
        eB[h * NN + i] = f2h16(exp2f(pr * LOG2E));          // exp(sr)
        eD[h * NN + i] = f2h16(exp2f(0.2f * pr * LOG2E));   // exp(0.2 sr)
        Rw[i * NH + h] = exp2f(-0.8f * pl * LOG2E);         // exp(-0.8 sl)
    }
}

// ---------------- kernel 2: MFMA flash-attn, single-buffer / 8 blocks/CU -----
// R3: Gt single-buffered (17.4 KB LDS) -> 8 blocks/CU; NJS=8 so grid 2048 =
// exactly 8 blocks/CU = 32 waves/CU (VGPR 64 = the 32-wave budget). The
// per-chunk barrier stalls that left VALU at 26% are now hidden by 8
// independent barrier groups per CU. Register prefetch of next G-chunk+mask
// retained (issue after write-barrier, consume next iteration). Co-resident
// blocks share js -> eB/eD/gT columns stay L1-hot.
__global__ __launch_bounds__(256, 8) void k_attn(
    const uint4* __restrict__ emask, const short* __restrict__ gT,
    const short* __restrict__ eB, const short* __restrict__ eD,
    const float* __restrict__ Rw,
    float* __restrict__ numw, float* __restrict__ denw)
{
    __shared__ __align__(16) short Gt[64][136];  // 17.4 KB

    const int t = threadIdx.x, lane = t & 63, w = t >> 6;
    const int ml = lane & 15, quad = lane >> 4;
    const int m8 = ml & 7;
    const int i0 = blockIdx.x * 16;
    const int js = blockIdx.y;
    const int jbase = js * (NN / NJS);
    const int h0 = w, h1 = w + 4;
    const int qb4 = quad * 4;
    const bool mhi = (ml >= 8);
    const u32 one2 = 0x3C003C00u;                   // f16 {1.0, 1.0}
    const uint4 ones4 = (uint4){one2, one2, one2, one2};

    h2 Ri[2];
    {
        const f16 r0 = (f16)Rw[(i0 + ml) * NH + h0];
        const f16 r1 = (f16)Rw[(i0 + ml) * NH + h1];
        Ri[0] = (h2){r0, r0};
        Ri[1] = (h2){r1, r1};
    }

    const uint4* mrow = emask + (size_t)(i0 + ml) * (NN / 128) + js * NCHK;
    const short* bp0 = eB + (size_t)h0 * NN + jbase;
    const short* dp0 = eD + (size_t)h0 * NN + jbase;
    const short* bp1 = eB + (size_t)h1 * NN + jbase;
    const short* dp1 = eD + (size_t)h1 * NN + jbase;

    const int grow = t >> 3, gseg = (t & 7) * 16;   // 64 rows x 128 j coop stage
    const short* g0 = gT + (size_t)grow * NN + jbase;
    const short* g1 = gT + (size_t)(grow + 32) * NN + jbase;

    // stage chunk 0 into registers
    uint4 pg0 = *(const uint4*)&g0[gseg];
    uint4 pg1 = *(const uint4*)&g0[gseg + 8];
    uint4 pg2 = *(const uint4*)&g1[gseg];
    uint4 pg3 = *(const uint4*)&g1[gseg + 8];
    uint4 mw = mrow[0], pm;

    v4f acc[2];
    acc[0] = (v4f){0.f, 0.f, 0.f, 0.f};
    acc[1] = (v4f){0.f, 0.f, 0.f, 0.f};

    for (int c = 0; c < NCHK; ++c) {
        __syncthreads();                     // previous compute done reading Gt
        *(uint4*)&Gt[grow][gseg]          = pg0;   // vmcnt-waits on stage loads
        *(uint4*)&Gt[grow][gseg + 8]      = pg1;
        *(uint4*)&Gt[grow + 32][gseg]     = pg2;
        *(uint4*)&Gt[grow + 32][gseg + 8] = pg3;
        __syncthreads();                     // Gt visible to all waves
        const bool pf = (c + 1) < NCHK;
        if (pf) {   // issue next chunk's loads early; consumed at next iter top
            const int jn = (c + 1) * 128;
            pg0 = *(const uint4*)&g0[jn + gseg];
            pg1 = *(const uint4*)&g0[jn + gseg + 8];
            pg2 = *(const uint4*)&g1[jn + gseg];
            pg3 = *(const uint4*)&g1[jn + gseg + 8];
            pm  = mrow[c + 1];
        }
#pragma unroll
        for (int s = 0; s < 4; ++s) {
            const int j0 = c * 128 + s * 32 + quad * 8;
            const uint4 bu0 = *(const uint4*)&bp0[j0];   // direct global (L1)
            const uint4 du0 = *(const uint4*)&dp0[j0];
            const uint4 bu1 = *(const uint4*)&bp1[j0];
            const uint4 du1 = *(const uint4*)&dp1[j0];
            const uint4 gu0 = *(const uint4*)&Gt[h0 * 8 + m8][s * 32 + quad * 8];
            const uint4 gu1 = *(const uint4*)&Gt[h1 * 8 + m8][s * 32 + quad * 8];
            const int base = ((s & 1) << 4) + qb4;
            const u32 WA = ((s >> 1) ? mw.y : mw.x) >> base;   // even-j bits
            const u32 WB = ((s >> 1) ? mw.w : mw.z) >> base;   // odd-j bits
            u32 m[4];
#pragma unroll
            for (int k = 0; k < 4; ++k) {
                const int ea = SBFE1(WA, k);            // 0 or 0xFFFFFFFF
                const int eb = SBFE1(WB, k);
                m[k] = __builtin_amdgcn_perm((u32)eb, (u32)ea, 0x05040100u);
            }
            u32 aw0[4], aw1[4];
#pragma unroll
            for (int k = 0; k < 4; ++k) {
                const u32 rd0 = h22u(Ri[0] * u2h2((&du0.x)[k]));   // v_pk_mul_f16
                const u32 rd1 = h22u(Ri[1] * u2h2((&du1.x)[k]));
                u32 p0, p1;
                asm("v_pk_max_f16 %0, %1, %2" : "=v"(p0) : "v"(rd0), "v"((&bu0.x)[k]));
                asm("v_pk_max_f16 %0, %1, %2" : "=v"(p1) : "v"(rd1), "v"((&bu1.x)[k]));
                aw0[k] = p0 & m[k];
                aw1[k] = p1 & m[k];
            }
            union { uint4 u; f16x8 h; } a0u, a1u, g0u, g1u;
            a0u.u = (uint4){aw0[0], aw0[1], aw0[2], aw0[3]};
            a1u.u = (uint4){aw1[0], aw1[1], aw1[2], aw1[3]};
            g0u.u = mhi ? ones4 : gu0;            // col 8 = ones (denominator)
            g1u.u = mhi ? ones4 : gu1;
            acc[0] = __builtin_amdgcn_mfma_f32_16x16x32_f16(a0u.h, g0u.h, acc[0], 0, 0, 0);
            acc[1] = __builtin_amdgcn_mfma_f32_16x16x32_f16(a1u.h, g1u.h, acc[1], 0, 0, 0);
        }
        if (pf) mw = pm;
    }

    // C layout: col = ml (0..7 dims, 8 = denominator), row = quad*4 + r
    float* nw = numw + (size_t)js * NN * HD;
    float* dw = denw + (size_t)js * NN * NH;
    const int ibase = i0 + quad * 4;
#pragma unroll
    for (int hh = 0; hh < 2; ++hh) {
        const int h = w + hh * 4;
#pragma unroll
        for (int r = 0; r < 4; ++r) {
            if (ml < 8)       nw[(ibase + r) * HD + h * 8 + ml] = acc[hh][r];
            else if (ml == 8) dw[(ibase + r) * NH + h]          = acc[hh][r];
        }
    }
}

// ---------------- kernel 3: combine j-split partials, div, ELU ---------------
__global__ __launch_bounds__(256) void k_comb(
    const float* __restrict__ numw, const float* __restrict__ denw,
    float* __restrict__ out)
{
    const int gid = blockIdx.x * 256 + threadIdx.x;   // 0 .. NN*HD-1
    const int i = gid >> 6, h = (gid & 63) >> 3;
    float num = 0.f, den = 0.f;
#pragma unroll
    for (int s = 0; s < NJS; ++s) {
        num += numw[s * NN * HD + gid];
        den += denw[s * NN * NH + i * NH + h];
    }
    float x = num / den;
    out[gid] = (x > 0.f) ? x : (__expf(x) - 1.f);     // ELU
}

extern "C" void kernel_launch(void* const* d_in, const int* in_sizes, int n_in,
                              void* d_out, int out_size, void* d_ws, size_t ws_size,
                              hipStream_t stream) {
    const float* vert = (const float*)d_in[0];
    const int*   edge = (const int*)d_in[1];
    const float* W    = (const float*)d_in[2];
    const float* al   = (const float*)d_in[3];
    const float* ar   = (const float*)d_in[4];
    float* out = (float*)d_out;

    char* ws = (char*)d_ws;
    short* gT    = (short*)ws;                          // 512 KB f16 g^T
    short* eB    = (short*)(ws + 512 * 1024);           // 64 KB
    short* eD    = (short*)(ws + 576 * 1024);           // 64 KB
    float* Rw    = (float*)(ws + 640 * 1024);           // 128 KB
    short* Wt    = (short*)(ws + 768 * 1024);           // 184 KB
    uint4* emask = (uint4*)(ws + 1024 * 1024);          // 2 MB edge bitmask
    float* Cp    = (float*)(ws + 3 * 1024 * 1024);      // 4 MB gemm K-partials
    float* numw  = (float*)(ws + 7 * 1024 * 1024);      // 8 MB (8 j-splits)
    float* denw  = (float*)(ws + 15 * 1024 * 1024);     // 1 MB

    hipLaunchKernelGGL(k_eprep, dim3(NN), dim3(256), 0, stream, edge, emask);
    hipLaunchKernelGGL(k_wprep, dim3(23), dim3(256), 0, stream, W, Wt);
    hipLaunchKernelGGL(k_gemm, dim3(NN / 16, NKS), dim3(256), 0, stream,
                       vert, Wt, Cp);
    hipLaunchKernelGGL(k_gpost, dim3(NN * 16 / 256), dim3(256), 0, stream,
                       Cp, al, ar, gT, eB, eD, Rw);
    hipLaunchKernelGGL(k_attn, dim3(NN / 16, NJS), dim3(256), 0, stream,
                       emask, gT, eB, eD, Rw, numw, denw);
    hipLaunchKernelGGL(k_comb, dim3(NN * HD / 256), dim3(256), 0, stream,
                       numw, denw, out);
}

// Round 4
// 153.778 us; speedup vs baseline: 1.2822x; 1.0500x over previous
//
#include <hip/hip_runtime.h>
#include <hip/hip_bf16.h>

#define NN 4096      // n_nodes
#define FIN 1433     // in features
#define NH 8         // heads
#define DH 8         // per-head dim
#define HD 64        // NH*DH
#define KP 1472      // K padded to 46*32
#define LOG2E 1.44269504f
#define NJS 8        // j-splits: grid 2048 = exactly 8 blocks/CU
#define NCHK ((NN / NJS) / 128)   // 4 chunks of 128 j per block
#define NKS 4        // gemm K-splits: grid 1024 = 4 blocks/CU

typedef unsigned int u32;
typedef unsigned long long u64;
typedef float v4f __attribute__((ext_vector_type(4)));
typedef _Float16 f16;
typedef _Float16 h2 __attribute__((ext_vector_type(2)));
typedef _Float16 f16x8 __attribute__((ext_vector_type(8)));

static __device__ __forceinline__ short f2h16(float f) {
    union { f16 h; short s; } u; u.h = (f16)f; return u.s;
}
static __device__ __forceinline__ h2 u2h2(u32 x) {
    union { u32 u; h2 h; } v; v.u = x; return v.h;
}
static __device__ __forceinline__ u32 h22u(h2 x) {
    union { h2 h; u32 u; } v; v.h = x; return v.u;
}

#if __has_builtin(__builtin_amdgcn_sbfe)
#define SBFE1(x, k) __builtin_amdgcn_sbfe((int)(x), (k), 1)
#else
#define SBFE1(x, k) (((int)((x) << (31 - (k)))) >> 31)
#endif

// async global->LDS DMA, 16B per lane; LDS dest = wave-uniform base + lane*16,
// global src is per-lane (llvm.amdgcn.global.load.lds: AS(1) src, AS(3) dst).
static __device__ __forceinline__ void gload_lds16(const void* g, void* l) {
    __builtin_amdgcn_global_load_lds(
        (const __attribute__((address_space(1))) void*)g,
        (__attribute__((address_space(3))) void*)l, 16, 0, 0);
}

// ---------------- kernel e: edge -> bitmask, R12 bit layout ------------------
// Per (row, 128-j chunk): uint4 { evenA_lo, evenA_hi, oddB_lo, oddB_hi }.
// 67 MB streamed once, coalesced int2 (8 B/lane). At the HBM BW floor (~11us).
__global__ __launch_bounds__(256) void k_eprep(const int* __restrict__ edge,
                                               uint4* __restrict__ emask) {
    const int t = threadIdx.x, lane = t & 63, w = t >> 6;
    const int row = blockIdx.x;
    const int* erow = edge + (size_t)row * NN;
    uint4* mrow = emask + (size_t)row * (NN / 128);
#pragma unroll
    for (int it = 0; it < 8; ++it) {
        const int ck = w * 8 + it;            // 4 waves x 8 = 32 chunks/row
        const int2 e2 = *(const int2*)&erow[ck * 128 + 2 * lane];
        const u64 bA = __ballot(e2.x != 0);
        const u64 bB = __ballot(e2.y != 0);
        if (lane == 0)
            mrow[ck] = (uint4){(u32)bA, (u32)(bA >> 32), (u32)bB, (u32)(bB >> 32)};
    }
}

// ---------------- kernel 0: Wt[n][k] = f16(W[k][n]), k zero-padded to 1472 ---
__global__ __launch_bounds__(256) void k_wprep(const float* __restrict__ W,
                                               short* __restrict__ Wt) {
    __shared__ float Ts[64][65];
    const int c = blockIdx.x;
    const int u = threadIdx.x;
    const int n4 = (u & 15) * 4;
    const int kr = u >> 4;
#pragma unroll
    for (int q = 0; q < 4; ++q) {
        const int kl = kr + q * 16;
        const int kg = c * 64 + kl;
        v4f v = {0.f, 0.f, 0.f, 0.f};
        if (kg < FIN) v = *(const v4f*)&W[(size_t)kg * HD + n4];
        *(v4f*)&Ts[kl][n4] = v;
    }
    __syncthreads();
    const int n = u >> 2;
    const int koff = (u & 3) * 16;
    __align__(16) short tmp[16];
#pragma unroll
    for (int r = 0; r < 16; ++r) tmp[r] = f2h16(Ts[koff + r][n]);
    *(uint4*)&Wt[(size_t)n * KP + c * 64 + koff]     = *(uint4*)&tmp[0];
    *(uint4*)&Wt[(size_t)n * KP + c * 64 + koff + 8] = *(uint4*)&tmp[8];
}

// ---------------- kernel 1: g = vert @ W, K-split x4 across blocks -----------
__global__ __launch_bounds__(256, 4) void k_gemm(
    const float* __restrict__ vert, const short* __restrict__ Wt,
    float* __restrict__ Cp)
{
    __shared__ float cacc[4][16][68];   // 17.4 KB

    const int t = threadIdx.x, lane = t & 63, w = t >> 6;
    const int ml = lane & 15, q = lane >> 4;
    const int i0 = blockIdx.x * 16;
    const int ks = blockIdx.y;
    const float* vrow = vert + (size_t)(i0 + ml) * FIN;

    v4f acc[4];
#pragma unroll
    for (int g = 0; g < 4; ++g) acc[g] = (v4f){0.f, 0.f, 0.f, 0.f};

    for (int c = ks + 4 * w; c < 45; c += 16) {
        const int k0 = c * 32 + q * 8;
        v4f a0, a1;
        if (k0 + 7 < FIN) {
            a0 = *(const v4f*)&vrow[k0];
            a1 = *(const v4f*)&vrow[k0 + 4];
        } else {
            float tmp[8];
#pragma unroll
            for (int e = 0; e < 8; ++e)
                tmp[e] = (k0 + e < FIN) ? vrow[k0 + e] : 0.f;
            a0 = (v4f){tmp[0], tmp[1], tmp[2], tmp[3]};
            a1 = (v4f){tmp[4], tmp[5], tmp[6], tmp[7]};
        }
        const f16x8 af = {(f16)a0.x, (f16)a0.y, (f16)a0.z, (f16)a0.w,
                          (f16)a1.x, (f16)a1.y, (f16)a1.z, (f16)a1.w};
#pragma unroll
        for (int g = 0; g < 4; ++g) {
            const f16x8 bf = *(const f16x8*)&Wt[(size_t)(g * 16 + ml) * KP + k0];
            acc[g] = __builtin_amdgcn_mfma_f32_16x16x32_f16(af, bf, acc[g], 0, 0, 0);
        }
    }

#pragma unroll
    for (int g = 0; g < 4; ++g)
#pragma unroll
        for (int r = 0; r < 4; ++r)
            cacc[w][q * 4 + r][g * 16 + ml] = acc[g][r];
    __syncthreads();

    const int m = t >> 4, n4 = (t & 15) * 4;
    v4f s = (v4f){0.f, 0.f, 0.f, 0.f};
#pragma unroll
    for (int ww = 0; ww < 4; ++ww) s += *(const v4f*)&cacc[ww][m][n4];
    *(v4f*)&Cp[((size_t)ks * NN + i0 + m) * HD + n4] = s;
}

// ---------------- kernel 1b: reduce K-partials + epilogue --------------------
__global__ __launch_bounds__(256) void k_gpost(
    const float* __restrict__ Cp,
    const float* __restrict__ al, const float* __restrict__ ar,
    short* __restrict__ gT, short* __restrict__ eB, short* __restrict__ eD,
    float* __restrict__ Rw)
{
    const int t = threadIdx.x;
    const int gid = blockIdx.x * 256 + t;        // 0 .. NN*16-1
    const int i = gid >> 4, n4 = (gid & 15) * 4;

    v4f s = (v4f){0.f, 0.f, 0.f, 0.f};
#pragma unroll
    for (int ks = 0; ks < NKS; ++ks)
        s += *(const v4f*)&Cp[((size_t)ks * NN + i) * HD + n4];

#pragma unroll
    for (int e = 0; e < 4; ++e)        // transposed store: gT[hd][node]
        gT[(size_t)(n4 + e) * NN + i] = f2h16(s[e]);

    float pl = s.x * al[n4] + s.y * al[n4 + 1] + s.z * al[n4 + 2] + s.w * al[n4 + 3];
    float pr = s.x * ar[n4] + s.y * ar[n4 + 1] + s.z * ar[n4 + 2] + s.w * ar[n4 + 3];
    pl += __shfl_xor(pl, 1, 64);
    pr += __shfl_xor(pr, 1, 64);
    if ((t & 1) == 0) {
        const int h = (t & 15) >> 1;
        eB[h * NN + i] = f2h16(exp2f(pr * LOG2E));          // exp(sr)
        eD[h * NN + i] = f2h16(exp2f(0.2f * pr * LOG2E));   // exp(0.2 sr)
        Rw[i * NH + h] = exp2f(-0.8f * pl * LOG2E);         // exp(-0.8 sl)
    }
}

// ---------------- kernel 2: MFMA flash-attn, DMA-staged, 8 blocks/CU ---------
// R4: all staging via global_load_lds (zero staging VGPRs -> no spill risk at
// the 64-VGPR/8-blocks-per-CU budget). Gs = G^T chunk [64 rows][128 j] f16,
// UNPADDED + XOR-swizzled (col ^= (row&7)*8) applied on BOTH the global source
// address and the LDS read (LDS dest linear, as the DMA requires) -> balanced
// banks on the b128 fragment reads. BDs = exp(sr)/exp(0.2sr) for all 8 heads
// (4 KB) staged per chunk -> the 16 per-chunk global B/D loads become
// broadcast LDS reads. LDS 20 KB x 8 blocks = 160 KB exactly; grid 2048 =
// exactly 8 blocks/CU = 32 waves/CU.
__global__ __launch_bounds__(256, 8) void k_attn(
    const uint4* __restrict__ emask, const short* __restrict__ gT,
    const short* __restrict__ eB, const short* __restrict__ eD,
    const float* __restrict__ Rw,
    float* __restrict__ numw, float* __restrict__ denw)
{
    __shared__ __align__(16) short Gs[64 * 128];   // 16 KB swizzled G chunk
    __shared__ __align__(16) short BDs[8 * 256];   // 4 KB: [h][B:128|D:128]

    const int t = threadIdx.x, lane = t & 63, w = t >> 6;
    const int ml = lane & 15, quad = lane >> 4;
    const int m8 = ml & 7;
    const int i0 = blockIdx.x * 16;
    const int js = blockIdx.y;
    const int jbase = js * (NN / NJS);
    const int h0 = w, h1 = w + 4;
    const int qb4 = quad * 4;
    const bool mhi = (ml >= 8);
    const u32 one2 = 0x3C003C00u;                   // f16 {1.0, 1.0}
    const uint4 ones4 = (uint4){one2, one2, one2, one2};

    h2 Ri[2];
    {
        const f16 r0 = (f16)Rw[(i0 + ml) * NH + h0];
        const f16 r1 = (f16)Rw[(i0 + ml) * NH + h1];
        Ri[0] = (h2){r0, r0};
        Ri[1] = (h2){r1, r1};
    }

    const uint4* mrow = emask + (size_t)(i0 + ml) * (NN / 128) + js * NCHK;

    // --- G staging geometry: round r stages 16B unit u = r*256 + t ----------
    // row = u>>4, col = (u&15)*8 ^ ((row&7)*8)  (source pre-swizzled)
    const short* gsrc[4];
#pragma unroll
    for (int r = 0; r < 4; ++r) {
        const int u = r * 256 + t;
        const int row = u >> 4;
        const int col = ((u & 15) * 8) ^ ((row & 7) * 8);
        gsrc[r] = gT + (size_t)row * NN + jbase + col;
    }
    // --- B/D staging: unit t -> head t>>5, slot t&31 (0-15 = B, 16-31 = D) --
    const int bh2 = t >> 5, bk = t & 31;
    const short* bdsrc = (bk < 16 ? eB : eD) + (size_t)bh2 * NN + jbase + (bk & 15) * 8;
    char* const gdst = (char*)Gs + (t & ~63) * 16;     // wave-uniform bases
    char* const bddst = (char*)BDs + (t & ~63) * 16;

    v4f acc[2];
    acc[0] = (v4f){0.f, 0.f, 0.f, 0.f};
    acc[1] = (v4f){0.f, 0.f, 0.f, 0.f};

    for (int c = 0; c < NCHK; ++c) {
        const int jc = c * 128;
#pragma unroll
        for (int r = 0; r < 4; ++r)
            gload_lds16(gsrc[r] + jc, (char*)Gs + r * 4096 + (t & ~63) * 16);
        gload_lds16(bdsrc + jc, bddst);
        const uint4 mw = mrow[c];             // 128 mask bits for this chunk
        __syncthreads();                      // drains vmcnt -> LDS valid
#pragma unroll
        for (int s = 0; s < 4; ++s) {
            const int xj = s * 32 + quad * 8;
            const int xg = xj ^ (m8 * 8);     // read-side swizzle
            const uint4 gu0 = *(const uint4*)&Gs[(h0 * 8 + m8) * 128 + xg];
            const uint4 gu1 = *(const uint4*)&Gs[(h1 * 8 + m8) * 128 + xg];
            const uint4 bu0 = *(const uint4*)&BDs[h0 * 256 + xj];
            const uint4 du0 = *(const uint4*)&BDs[h0 * 256 + 128 + xj];
            const uint4 bu1 = *(const uint4*)&BDs[h1 * 256 + xj];
            const uint4 du1 = *(const uint4*)&BDs[h1 * 256 + 128 + xj];
            const int base = ((s & 1) << 4) + qb4;
            const u32 WA = ((s >> 1) ? mw.y : mw.x) >> base;   // even-j bits
            const u32 WB = ((s >> 1) ? mw.w : mw.z) >> base;   // odd-j bits
            u32 m[4];
#pragma unroll
            for (int k = 0; k < 4; ++k) {
                const int ea = SBFE1(WA, k);            // 0 or 0xFFFFFFFF
                const int eb = SBFE1(WB, k);
                m[k] = __builtin_amdgcn_perm((u32)eb, (u32)ea, 0x05040100u);
            }
            u32 aw0[4], aw1[4];
#pragma unroll
            for (int k = 0; k < 4; ++k) {
                const u32 rd0 = h22u(Ri[0] * u2h2((&du0.x)[k]));   // v_pk_mul_f16
                const u32 rd1 = h22u(Ri[1] * u2h2((&du1.x)[k]));
                u32 p0, p1;
                asm("v_pk_max_f16 %0, %1, %2" : "=v"(p0) : "v"(rd0), "v"((&bu0.x)[k]));
                asm("v_pk_max_f16 %0, %1, %2" : "=v"(p1) : "v"(rd1), "v"((&bu1.x)[k]));
                aw0[k] = p0 & m[k];
                aw1[k] = p1 & m[k];
            }
            union { uint4 u; f16x8 h; } a0u, a1u, g0u, g1u;
            a0u.u = (uint4){aw0[0], aw0[1], aw0[2], aw0[3]};
            a1u.u = (uint4){aw1[0], aw1[1], aw1[2], aw1[3]};
            g0u.u = mhi ? ones4 : gu0;            // col 8 = ones (denominator)
            g1u.u = mhi ? ones4 : gu1;
            acc[0] = __builtin_amdgcn_mfma_f32_16x16x32_f16(a0u.h, g0u.h, acc[0], 0, 0, 0);
            acc[1] = __builtin_amdgcn_mfma_f32_16x16x32_f16(a1u.h, g1u.h, acc[1], 0, 0, 0);
        }
        __syncthreads();                      // all waves done reading LDS
    }

    // C layout: col = ml (0..7 dims, 8 = denominator), row = quad*4 + r
    float* nw = numw + (size_t)js * NN * HD;
    float* dw = denw + (size_t)js * NN * NH;
    const int ibase = i0 + quad * 4;
#pragma unroll
    for (int hh = 0; hh < 2; ++hh) {
        const int h = w + hh * 4;
#pragma unroll
        for (int r = 0; r < 4; ++r) {
            if (ml < 8)       nw[(ibase + r) * HD + h * 8 + ml] = acc[hh][r];
            else if (ml == 8) dw[(ibase + r) * NH + h]          = acc[hh][r];
        }
    }
}

// ---------------- kernel 3: combine j-split partials, div, ELU ---------------
__global__ __launch_bounds__(256) void k_comb(
    const float* __restrict__ numw, const float* __restrict__ denw,
    float* __restrict__ out)
{
    const int gid = blockIdx.x * 256 + threadIdx.x;   // 0 .. NN*HD-1
    const int i = gid >> 6, h = (gid & 63) >> 3;
    float num = 0.f, den = 0.f;
#pragma unroll
    for (int s = 0; s < NJS; ++s) {
        num += numw[s * NN * HD + gid];
        den += denw[s * NN * NH + i * NH + h];
    }
    float x = num / den;
    out[gid] = (x > 0.f) ? x : (__expf(x) - 1.f);     // ELU
}

extern "C" void kernel_launch(void* const* d_in, const int* in_sizes, int n_in,
                              void* d_out, int out_size, void* d_ws, size_t ws_size,
                              hipStream_t stream) {
    const float* vert = (const float*)d_in[0];
    const int*   edge = (const int*)d_in[1];
    const float* W    = (const float*)d_in[2];
    const float* al   = (const float*)d_in[3];
    const float* ar   = (const float*)d_in[4];
    float* out = (float*)d_out;

    char* ws = (char*)d_ws;
    short* gT    = (short*)ws;                          // 512 KB f16 g^T
    short* eB    = (short*)(ws + 512 * 1024);           // 64 KB
    short* eD    = (short*)(ws + 576 * 1024);           // 64 KB
    float* Rw    = (float*)(ws + 640 * 1024);           // 128 KB
    short* Wt    = (short*)(ws + 768 * 1024);           // 184 KB
    uint4* emask = (uint4*)(ws + 1024 * 1024);          // 2 MB edge bitmask
    float* Cp    = (float*)(ws + 3 * 1024 * 1024);      // 4 MB gemm K-partials
    float* numw  = (float*)(ws + 7 * 1024 * 1024);      // 8 MB (8 j-splits)
    float* denw  = (float*)(ws + 15 * 1024 * 1024);     // 1 MB

    hipLaunchKernelGGL(k_eprep, dim3(NN), dim3(256), 0, stream, edge, emask);
    hipLaunchKernelGGL(k_wprep, dim3(23), dim3(256), 0, stream, W, Wt);
    hipLaunchKernelGGL(k_gemm, dim3(NN / 16, NKS), dim3(256), 0, stream,
                       vert, Wt, Cp);
    hipLaunchKernelGGL(k_gpost, dim3(NN * 16 / 256), dim3(256), 0, stream,
                       Cp, al, ar, gT, eB, eD, Rw);
    hipLaunchKernelGGL(k_attn, dim3(NN / 16, NJS), dim3(256), 0, stream,
                       emask, gT, eB, eD, Rw, numw, denw);
    hipLaunchKernelGGL(k_comb, dim3(NN * HD / 256), dim3(256), 0, stream,
                       numw, denw, out);
}